// Round 4
// baseline (352.118 us; speedup 1.0000x reference)
//
#include <hip/hip_runtime.h>
#include <hip/hip_bf16.h>
#include <stdint.h>

#define B_ 4
#define S_ 4096
#define E_ 1024
#define H_ 16
#define D_ 64
#define M_ (B_*S_)          // 16384 rows
constexpr float kEPS = 1e-6f;

typedef unsigned short u16;
typedef unsigned char  u8;
typedef __bf16 bf16x8 __attribute__((ext_vector_type(8)));
typedef float  f32x4  __attribute__((ext_vector_type(4)));
typedef u16    u16x8  __attribute__((ext_vector_type(8)));

typedef const __attribute__((address_space(1))) void* gaddr_t;
typedef __attribute__((address_space(3))) void*       laddr_t;

__device__ __forceinline__ u16 f2bf(float f) {
    union { float f; uint32_t u; } v; v.f = f;
    uint32_t u = v.u;
    u += 0x7fffu + ((u >> 16) & 1u);   // RNE
    return (u16)(u >> 16);
}
__device__ __forceinline__ float bf2f(u16 h) {
    union { uint32_t u; float f; } v; v.u = ((uint32_t)h) << 16;
    return v.f;
}
__device__ __forceinline__ float hi2f(uint32_t d) {
    union { uint32_t u; float f; } v; v.u = d & 0xffff0000u;
    return v.f;
}
__device__ __forceinline__ float lo2f(uint32_t d) {
    union { uint32_t u; float f; } v; v.u = d << 16;
    return v.f;
}

#define VM_WAIT(n) asm volatile("s_waitcnt vmcnt(" #n ")" ::: "memory")
#define LG0        asm volatile("s_waitcnt lgkmcnt(0)" ::: "memory")

// ---------------- f32 -> bf16 conversion ----------------
__global__ void cvt_kernel(const float* __restrict__ in, u16* __restrict__ out, int n4) {
    int i = blockIdx.x * blockDim.x + threadIdx.x;
    if (i >= n4) return;
    float4 v = reinterpret_cast<const float4*>(in)[i];
    ushort4 o;
    o.x = f2bf(v.x); o.y = f2bf(v.y); o.z = f2bf(v.z); o.w = f2bf(v.w);
    reinterpret_cast<ushort4*>(out)[i] = o;
}

// ================= 8-phase 256x256 GEMM, C = A @ W^T =================
// A: [M][1024] bf16 row-major. Bw: [1024][1024] bf16 row-major (weight).
// K-tile BK=64, 16 tiles. 2 LDS buffers (full K-tile each, A+B = 64 KB).
// Per K-tile 4 phases: (ks0,mlo)(ks0,mhi)(ks1,mlo)(ks1,mhi); each phase
// stages ONE granule (matrix x ks-slice, 16 KB) of tile t+1 into the other
// buffer; vmcnt(4) at odd phases keeps 4 loads always in flight.
// EPI: 0 = f32 out + bias; 1 = relu(x+b)+eps -> bf16; 2 = EPI1+mask; 3 = x+b -> bf16
#define BM 256
#define BN 256
#define BKT 64
#define NKT (E_/BKT)        // 16 K-tiles
// LDS u16 offsets: dbuf stride 32768; within dbuf: A at 0, B at 16384; granule ks*8192.

template<int EPI>
__global__ __launch_bounds__(512, 2)
void gemm8(const u16* __restrict__ A, const u16* __restrict__ Bw,
           const float* __restrict__ bias, const u8* __restrict__ mask,
           float* __restrict__ Cf, u16* __restrict__ Cb)
{
    extern __shared__ u16 lds[];   // 65536 u16 = 128 KB
    const int tid  = threadIdx.x;
    const int wid  = tid >> 6, lane = tid & 63;
    const int wr   = wid >> 2, wc = wid & 3;      // 2M x 4N waves
    const int m0   = blockIdx.x * BM;
    const int n0   = blockIdx.y * BN;
    const int fr   = lane & 15;
    const int cg   = lane >> 4;
    const int lkey = (fr ^ (fr >> 2)) & 3;

    // ---- staging geometry: granule = 1024 slots (16B); slot s -> row=s>>2, stored chunk sc=s&3,
    //      content chunk = sc ^ key(row), key(row) = (row ^ (row>>2)) & 3
    const int srow = tid >> 2;                               // 0..127 (slot tid) / +128 (slot tid+512)
    const int skey = (srow ^ (srow >> 2)) & 3;               // same for srow+128
    const int scg  = (tid & 3) ^ skey;
    const u16* a0p = A  + (size_t)(m0 + srow)*E_       + scg*8;
    const u16* a1p = A  + (size_t)(m0 + srow + 128)*E_ + scg*8;
    const u16* b0p = Bw + (size_t)(n0 + srow)*E_       + scg*8;
    const u16* b1p = Bw + (size_t)(n0 + srow + 128)*E_ + scg*8;
    const int d0 = tid*8, d1 = (tid + 512)*8;                // LDS u16 offsets within granule

    // ---- fragment read offsets (u16): slot = row*4 + (cg ^ key(row)); key(row)=lkey for our rows
    const int aoff0 = (wr*128 + fr)*32 + ((cg ^ lkey) * 8);
    const int boff0 = (wc*64  + fr)*32 + ((cg ^ lkey) * 8);

    f32x4 acc[8][4] = {};

    float bias_v[4];
#pragma unroll
    for (int nf = 0; nf < 4; ++nf) bias_v[nf] = bias[n0 + wc*64 + nf*16 + fr];

    // stage granule (STB: 0=A,1=B; ks-slice STKS) of tile TN into dbuf DB
#define STAGE_G(DB, TN, STB, STKS) do { \
        u16* sd_ = lds + (DB)*32768 + ((STB) ? 16384 : 0) + (STKS)*8192; \
        const int ko_ = ((TN)&15)*BKT + (STKS)*32; \
        if (STB) { \
            __builtin_amdgcn_global_load_lds((gaddr_t)(b0p + ko_), (laddr_t)(sd_ + d0), 16, 0, 0); \
            __builtin_amdgcn_global_load_lds((gaddr_t)(b1p + ko_), (laddr_t)(sd_ + d1), 16, 0, 0); \
        } else { \
            __builtin_amdgcn_global_load_lds((gaddr_t)(a0p + ko_), (laddr_t)(sd_ + d0), 16, 0, 0); \
            __builtin_amdgcn_global_load_lds((gaddr_t)(a1p + ko_), (laddr_t)(sd_ + d1), 16, 0, 0); \
        } } while (0)

    // one phase: reads + stage + (wait) + barrier + 16 MFMA
#define PHASE(CB, T, KS, MH, STB, STKS) do { \
        const u16* Ab_ = lds + (CB)*32768 + (KS)*8192; \
        const u16* Bb_ = lds + (CB)*32768 + 16384 + (KS)*8192; \
        bf16x8 bf_[4], af_[4]; \
        bf_[0] = *reinterpret_cast<const bf16x8*>(Bb_ + boff0 + 0*512); \
        bf_[1] = *reinterpret_cast<const bf16x8*>(Bb_ + boff0 + 1*512); \
        bf_[2] = *reinterpret_cast<const bf16x8*>(Bb_ + boff0 + 2*512); \
        bf_[3] = *reinterpret_cast<const bf16x8*>(Bb_ + boff0 + 3*512); \
        af_[0] = *reinterpret_cast<const bf16x8*>(Ab_ + aoff0 + ((MH)*4+0)*512); \
        af_[1] = *reinterpret_cast<const bf16x8*>(Ab_ + aoff0 + ((MH)*4+1)*512); \
        af_[2] = *reinterpret_cast<const bf16x8*>(Ab_ + aoff0 + ((MH)*4+2)*512); \
        af_[3] = *reinterpret_cast<const bf16x8*>(Ab_ + aoff0 + ((MH)*4+3)*512); \
        STAGE_G((CB)^1, (T)+1, STB, STKS); \
        if ((MH) == 1) VM_WAIT(4); \
        LG0; \
        __builtin_amdgcn_sched_barrier(0); \
        __builtin_amdgcn_s_barrier(); \
        __builtin_amdgcn_s_setprio(1); \
        _Pragma("unroll") \
        for (int i_ = 0; i_ < 4; ++i_) { \
            _Pragma("unroll") \
            for (int j_ = 0; j_ < 4; ++j_) \
                acc[(MH)*4+i_][j_] = __builtin_amdgcn_mfma_f32_16x16x32_bf16(af_[i_], bf_[j_], acc[(MH)*4+i_][j_], 0, 0, 0); \
        } \
        __builtin_amdgcn_s_setprio(0); \
    } while (0)

    // prologue: full tile 0 into dbuf 0
    STAGE_G(0, 0, 0, 0);
    STAGE_G(0, 0, 1, 0);
    STAGE_G(0, 0, 0, 1);
    STAGE_G(0, 0, 1, 1);
    VM_WAIT(0);
    __builtin_amdgcn_s_barrier();
    __builtin_amdgcn_sched_barrier(0);

#pragma unroll 1
    for (int tp = 0; tp < NKT/2; ++tp) {
        const int t0 = tp*2, t1 = tp*2 + 1;
        PHASE(0, t0, 0, 0, 0, 0);
        PHASE(0, t0, 0, 1, 1, 0);
        PHASE(0, t0, 1, 0, 0, 1);
        PHASE(0, t0, 1, 1, 1, 1);
        PHASE(1, t1, 0, 0, 0, 0);
        PHASE(1, t1, 0, 1, 1, 0);
        PHASE(1, t1, 1, 0, 0, 1);
        PHASE(1, t1, 1, 1, 1, 1);
    }
#undef PHASE
#undef STAGE_G

    // ---- epilogue ----
#pragma unroll
    for (int mf = 0; mf < 8; ++mf) {
#pragma unroll
        for (int nf = 0; nf < 4; ++nf) {
            const int gn = n0 + wc*64 + nf*16 + fr;
#pragma unroll
            for (int r = 0; r < 4; ++r) {
                const int gm = m0 + wr*128 + mf*16 + cg*4 + r;
                float x = acc[mf][nf][r] + bias_v[nf];
                if (EPI == 0) {
                    Cf[(size_t)gm*E_ + gn] = x;
                } else if (EPI == 1) {
                    x = fmaxf(x, 0.f) + kEPS;
                    Cb[(size_t)gm*E_ + gn] = f2bf(x);
                } else if (EPI == 2) {
                    x = fmaxf(x, 0.f) + kEPS;
                    if (mask[gm]) x = 0.f;
                    Cb[(size_t)gm*E_ + gn] = f2bf(x);
                } else {
                    Cb[(size_t)gm*E_ + gn] = f2bf(x);
                }
            }
        }
    }
}

// ---------------- stage 2: kv partial = K_chunk^T @ V_chunk ----------------
#define KVS 256             // s-rows per chunk
#define KVCH (S_/KVS)       // 16 chunks
#define KPAD 72             // padded row stride (u16)
__global__ __launch_bounds__(256)
void kv_partial_kernel(const u16* __restrict__ Ka, const u16* __restrict__ Vv,
                       float* __restrict__ kvp, float* __restrict__ ksp)
{
    __shared__ u16 Ks[KVS*KPAD];   // 36 KB
    __shared__ u16 Vs[KVS*KPAD];   // 36 KB
    const int bh = blockIdx.x, b = bh >> 4, h = bh & 15;
    const int s0 = blockIdx.y * KVS;
    const int tid = threadIdx.x;

#pragma unroll
    for (int i = 0; i < 8; ++i) {
        int g = i*256 + tid;
        int row = g >> 3, c8 = (g & 7) * 8;
        size_t goff = (size_t)(b*S_ + s0 + row)*E_ + h*64 + c8;
        *reinterpret_cast<uint4*>(Ks + row*KPAD + c8) = *reinterpret_cast<const uint4*>(Ka + goff);
        *reinterpret_cast<uint4*>(Vs + row*KPAD + c8) = *reinterpret_cast<const uint4*>(Vv + goff);
    }
    __syncthreads();

    const int dg = tid >> 4;
    const int vg = tid & 15;
    float acc[16] = {};
#pragma unroll 4
    for (int s = 0; s < KVS; ++s) {
        uint2 ku = *reinterpret_cast<const uint2*>(Ks + s*KPAD + dg*4);
        uint2 vu = *reinterpret_cast<const uint2*>(Vs + s*KPAD + vg*4);
        float k0 = lo2f(ku.x), k1 = hi2f(ku.x), k2 = lo2f(ku.y), k3 = hi2f(ku.y);
        float v0 = lo2f(vu.x), v1 = hi2f(vu.x), v2 = lo2f(vu.y), v3 = hi2f(vu.y);
        acc[0]  += k0*v0; acc[1]  += k0*v1; acc[2]  += k0*v2; acc[3]  += k0*v3;
        acc[4]  += k1*v0; acc[5]  += k1*v1; acc[6]  += k1*v2; acc[7]  += k1*v3;
        acc[8]  += k2*v0; acc[9]  += k2*v1; acc[10] += k2*v2; acc[11] += k2*v3;
        acc[12] += k3*v0; acc[13] += k3*v1; acc[14] += k3*v2; acc[15] += k3*v3;
    }
    float* dst = kvp + ((size_t)blockIdx.y*64 + bh)*4096;
#pragma unroll
    for (int i = 0; i < 4; ++i) {
        f32x4 o; o[0] = acc[i*4+0]; o[1] = acc[i*4+1]; o[2] = acc[i*4+2]; o[3] = acc[i*4+3];
        *reinterpret_cast<f32x4*>(dst + (dg*4+i)*64 + vg*4) = o;
    }

    __syncthreads();
    {
        const int col = tid & 63, grp = tid >> 6;
        float s = 0.f;
#pragma unroll 8
        for (int r = 0; r < 64; ++r) s += bf2f(Ks[(grp*64 + r)*KPAD + col]);
        ((float*)Vs)[grp*64 + col] = s;
    }
    __syncthreads();
    if (tid < 64) {
        const float* sc = (const float*)Vs;
        float t = sc[tid] + sc[64+tid] + sc[128+tid] + sc[192+tid];
        ksp[((size_t)blockIdx.y*64 + bh)*64 + tid] = t;
    }
}

// ---------------- stage 2b: reduce partials -> kvT (bf16) + ksum ----------------
__global__ __launch_bounds__(256)
void kv_reduce_kernel(const float* __restrict__ kvp, const float* __restrict__ ksp,
                      u16* __restrict__ kvT, float* __restrict__ ksum)
{
    __shared__ u16 T[64*KPAD];
    const int bh = blockIdx.x, tid = threadIdx.x;
#pragma unroll
    for (int j = 0; j < 16; ++j) {
        int idx = j*256 + tid;
        int d = idx >> 6, v = idx & 63;
        float s = 0.f;
#pragma unroll
        for (int c = 0; c < KVCH; ++c) s += kvp[((size_t)c*64 + bh)*4096 + idx];
        T[v*KPAD + d] = f2bf(s);
    }
    if (tid < 64) {
        float t = 0.f;
#pragma unroll
        for (int c = 0; c < KVCH; ++c) t += ksp[((size_t)c*64 + bh)*64 + tid];
        ksum[bh*64 + tid] = t;
    }
    __syncthreads();
#pragma unroll
    for (int k = 0; k < 2; ++k) {
        int g = k*256 + tid;
        int v = g >> 3, c8 = (g & 7) * 8;
        uint4 q = *reinterpret_cast<const uint4*>(T + v*KPAD + c8);
        *reinterpret_cast<uint4*>(kvT + (size_t)bh*4096 + g*8) = q;
    }
}

// ---------------- stage 3: attn = (Qa @ kv) / max(Qa . ksum, eps), MFMA ----------------
__global__ __launch_bounds__(256)
void attn_kernel(const u16* __restrict__ Qa, const u16* __restrict__ kvT,
                 const float* __restrict__ ksum, u16* __restrict__ attn)
{
    __shared__ u16  Qs[256*64];
    __shared__ u16  Ts[64*64];
    __shared__ float kss[64];
    __shared__ float invd[256];

    const int bh = blockIdx.x, b = bh >> 4, h = bh & 15;
    const int s0 = blockIdx.y * 256;
    const int tid = threadIdx.x;
    const int wid = tid >> 6, lane = tid & 63;
    const int fr = lane & 15, cg = lane >> 4;

#pragma unroll
    for (int j = 0; j < 8; ++j) {
        int L = (wid*8 + j)*64 + lane;
        int row = L >> 3, c = L & 7;
        int cs = c ^ (row & 7);
        const u16* src = Qa + (size_t)(b*S_ + s0 + row)*E_ + h*64 + cs*8;
        __builtin_amdgcn_global_load_lds((gaddr_t)src, (laddr_t)(Qs + L*8), 16, 0, 0);
    }
#pragma unroll
    for (int k = 0; k < 2; ++k) {
        int g = k*256 + tid;
        int v = g >> 3, c = g & 7;
        uint4 q = *reinterpret_cast<const uint4*>(kvT + (size_t)bh*4096 + g*8);
        int cs = c ^ (v & 7);
        *reinterpret_cast<uint4*>(Ts + v*64 + cs*8) = q;
    }
    if (tid < 64) kss[tid] = ksum[bh*64 + tid];
    asm volatile("s_waitcnt vmcnt(0) lgkmcnt(0)" ::: "memory");
    __syncthreads();

    {
        float den = 0.f;
#pragma unroll
        for (int c = 0; c < 8; ++c) {
            uint4 qc = *reinterpret_cast<const uint4*>(Qs + tid*64 + (c ^ (tid & 7))*8);
            den += lo2f(qc.x)*kss[c*8+0] + hi2f(qc.x)*kss[c*8+1]
                 + lo2f(qc.y)*kss[c*8+2] + hi2f(qc.y)*kss[c*8+3]
                 + lo2f(qc.z)*kss[c*8+4] + hi2f(qc.z)*kss[c*8+5]
                 + lo2f(qc.w)*kss[c*8+6] + hi2f(qc.w)*kss[c*8+7];
        }
        invd[tid] = 1.0f / fmaxf(den, kEPS);
    }
    __syncthreads();

    f32x4 acc[4][4] = {};
#pragma unroll
    for (int ks = 0; ks < 2; ++ks) {
        bf16x8 bfrag[4];
#pragma unroll
        for (int nf = 0; nf < 4; ++nf) {
            int v = nf*16 + fr;
            bfrag[nf] = *reinterpret_cast<const bf16x8*>(Ts + v*64 + ((ks*4 + cg) ^ (v & 7))*8);
        }
#pragma unroll
        for (int mf = 0; mf < 4; ++mf) {
            int m = wid*64 + mf*16 + fr;
            bf16x8 afrag = *reinterpret_cast<const bf16x8*>(Qs + m*64 + ((ks*4 + cg) ^ (m & 7))*8);
#pragma unroll
            for (int nf = 0; nf < 4; ++nf)
                acc[mf][nf] = __builtin_amdgcn_mfma_f32_16x16x32_bf16(afrag, bfrag[nf], acc[mf][nf], 0, 0, 0);
        }
    }

#pragma unroll
    for (int mf = 0; mf < 4; ++mf) {
#pragma unroll
        for (int nf = 0; nf < 4; ++nf) {
            const int v = nf*16 + fr;
#pragma unroll
            for (int r = 0; r < 4; ++r) {
                const int row = wid*64 + mf*16 + cg*4 + r;
                float x = acc[mf][nf][r] * invd[row];
                attn[(size_t)(b*S_ + s0 + row)*E_ + h*64 + v] = f2bf(x);
            }
        }
    }
}

// ---------------- host ----------------
extern "C" void kernel_launch(void* const* d_in, const int* in_sizes, int n_in,
                              void* d_out, int out_size, void* d_ws, size_t ws_size,
                              hipStream_t stream)
{
    const float* query = (const float*)d_in[0];
    const float* key   = (const float*)d_in[1];
    const float* value = (const float*)d_in[2];
    const u8*    mask  = (const u8*)d_in[3];
    const float* Wq = (const float*)d_in[4];
    const float* bq = (const float*)d_in[5];
    const float* Wk = (const float*)d_in[6];
    const float* bk = (const float*)d_in[7];
    const float* Wv = (const float*)d_in[8];
    const float* bv = (const float*)d_in[9];
    const float* Wo = (const float*)d_in[10];
    const float* bo = (const float*)d_in[11];
    float* out = (float*)d_out;

    const size_t SZ_ME = (size_t)M_ * E_;
    const size_t SZ_EE = (size_t)E_ * E_;

    char* ws = (char*)d_ws;
    u16* qx   = (u16*)ws; ws += SZ_ME*2;   // query bf16; reused for attnb
    u16* kx   = (u16*)ws; ws += SZ_ME*2;   // key bf16; reused for kvp
    u16* vx   = (u16*)ws; ws += SZ_ME*2;   // value bf16; reused for ksp/kvT/ksum
    u16* Qa   = (u16*)ws; ws += SZ_ME*2;
    u16* Ka   = (u16*)ws; ws += SZ_ME*2;
    u16* Vv   = (u16*)ws; ws += SZ_ME*2;
    u16* wqb  = (u16*)ws; ws += SZ_EE*2;
    u16* wkb  = (u16*)ws; ws += SZ_EE*2;
    u16* wvb  = (u16*)ws; ws += SZ_EE*2;
    u16* wob  = (u16*)ws; ws += SZ_EE*2;

    // overlays (dead by the time they're written)
    u16*   attnb = qx;                                   // after attn inputs consumed
    float* kvp   = (float*)kx;                           // 16 MiB (kx dead after Ka)
    float* ksp   = (float*)vx;                           // 256 KiB
    u16*   kvT   = (u16*)((char*)vx + (size_t)KVCH*64*64*4);          // 512 KiB
    float* ksum  = (float*)((char*)kvT + (size_t)64*4096*2);

    // 1) conversions to bf16
    cvt_kernel<<<(int)(SZ_ME/4/256), 256, 0, stream>>>(query, qx, (int)(SZ_ME/4));
    cvt_kernel<<<(int)(SZ_ME/4/256), 256, 0, stream>>>(key,   kx, (int)(SZ_ME/4));
    cvt_kernel<<<(int)(SZ_ME/4/256), 256, 0, stream>>>(value, vx, (int)(SZ_ME/4));
    cvt_kernel<<<(int)(SZ_EE/4/256), 256, 0, stream>>>(Wq, wqb, (int)(SZ_EE/4));
    cvt_kernel<<<(int)(SZ_EE/4/256), 256, 0, stream>>>(Wk, wkb, (int)(SZ_EE/4));
    cvt_kernel<<<(int)(SZ_EE/4/256), 256, 0, stream>>>(Wv, wvb, (int)(SZ_EE/4));
    cvt_kernel<<<(int)(SZ_EE/4/256), 256, 0, stream>>>(Wo, wob, (int)(SZ_EE/4));

    // 2) QKV projections (8-phase GEMM)
    dim3 ggrid(M_/BM, E_/BN);   // (64, 4): blocks sharing an A-panel are 64 apart -> same XCD
    constexpr size_t LDS_BYTES = 2 * 32768 * sizeof(u16);   // 128 KB
    gemm8<1><<<ggrid, 512, LDS_BYTES, stream>>>(qx, wqb, bq, nullptr, nullptr, Qa);
    gemm8<2><<<ggrid, 512, LDS_BYTES, stream>>>(kx, wkb, bk, mask,    nullptr, Ka);
    gemm8<3><<<ggrid, 512, LDS_BYTES, stream>>>(vx, wvb, bv, nullptr, nullptr, Vv);

    // 3) kv_context + k_sum (two-phase, deterministic)
    kv_partial_kernel<<<dim3(B_*H_, KVCH), 256, 0, stream>>>(Ka, Vv, kvp, ksp);
    kv_reduce_kernel<<<64, 256, 0, stream>>>(kvp, ksp, kvT, ksum);

    // 4) attn numerator / denom (MFMA)
    attn_kernel<<<dim3(B_*H_, S_/256), 256, 0, stream>>>(Qa, kvT, ksum, attnb);

    // 5) output projection -> f32 out
    gemm8<0><<<ggrid, 512, LDS_BYTES, stream>>>(attnb, wob, bo, nullptr, out, nullptr);
}

// Round 5
// 299.712 us; speedup vs baseline: 1.1749x; 1.1749x over previous
//
#include <hip/hip_runtime.h>
#include <hip/hip_bf16.h>
#include <stdint.h>

#define B_ 4
#define S_ 4096
#define E_ 1024
#define H_ 16
#define D_ 64
#define M_ (B_*S_)          // 16384 rows
constexpr float kEPS = 1e-6f;

typedef unsigned short u16;
typedef unsigned char  u8;
typedef __bf16 bf16x8 __attribute__((ext_vector_type(8)));
typedef float  f32x4  __attribute__((ext_vector_type(4)));
typedef u16    u16x8  __attribute__((ext_vector_type(8)));

typedef const __attribute__((address_space(1))) void* gaddr_t;
typedef __attribute__((address_space(3))) void*       laddr_t;

__device__ __forceinline__ u16 f2bf(float f) {
    union { float f; uint32_t u; } v; v.f = f;
    uint32_t u = v.u;
    u += 0x7fffu + ((u >> 16) & 1u);   // RNE
    return (u16)(u >> 16);
}
__device__ __forceinline__ float bf2f(u16 h) {
    union { uint32_t u; float f; } v; v.u = ((uint32_t)h) << 16;
    return v.f;
}
__device__ __forceinline__ float hi2f(uint32_t d) {
    union { uint32_t u; float f; } v; v.u = d & 0xffff0000u;
    return v.f;
}
__device__ __forceinline__ float lo2f(uint32_t d) {
    union { uint32_t u; float f; } v; v.u = d << 16;
    return v.f;
}

#define VM_WAIT(n) asm volatile("s_waitcnt vmcnt(" #n ")" ::: "memory")
#define LG0        asm volatile("s_waitcnt lgkmcnt(0)" ::: "memory")

// ---------------- f32 -> bf16 conversion ----------------
__global__ void cvt_kernel(const float* __restrict__ in, u16* __restrict__ out, int n4) {
    int i = blockIdx.x * blockDim.x + threadIdx.x;
    if (i >= n4) return;
    float4 v = reinterpret_cast<const float4*>(in)[i];
    ushort4 o;
    o.x = f2bf(v.x); o.y = f2bf(v.y); o.z = f2bf(v.z); o.w = f2bf(v.w);
    reinterpret_cast<ushort4*>(out)[i] = o;
}

// ================= 8-phase 256x256 GEMM, C = A @ W^T =================
// A: [M][1024] bf16 row-major. Bw: [1024][1024] bf16 row-major (weight).
// K-tile BK=64, 16 tiles. 2 LDS buffers (full K-tile each, A+B = 64 KB).
// Per K-tile 4 phases: (ks0,mlo)(ks0,mhi)(ks1,mlo)(ks1,mhi); each phase
// stages ONE granule (matrix x ks-slice, 16 KB) of tile t+1 into the other
// buffer; vmcnt(4) at odd phases keeps 4 loads always in flight.
// EPI: 0 = f32 out + bias; 1 = relu(x+b)+eps -> bf16; 2 = EPI1+mask; 3 = x+b -> bf16
#define BM 256
#define BN 256
#define BKT 64
#define NKT (E_/BKT)        // 16 K-tiles

template<int EPI>
__global__ __launch_bounds__(512, 2)
void gemm8(const u16* __restrict__ A, const u16* __restrict__ Bw,
           const float* __restrict__ bias, const u8* __restrict__ mask,
           float* __restrict__ Cf, u16* __restrict__ Cb)
{
    extern __shared__ u16 lds[];   // 65536 u16 = 128 KB
    const int tid  = threadIdx.x;
    const int wid  = tid >> 6, lane = tid & 63;
    const int wr   = wid >> 2, wc = wid & 3;      // 2M x 4N waves
    const int m0   = blockIdx.x * BM;
    const int n0   = blockIdx.y * BN;
    const int fr   = lane & 15;
    const int cg   = lane >> 4;
    const int lkey = (fr ^ (fr >> 2)) & 3;

    const int srow = tid >> 2;
    const int skey = (srow ^ (srow >> 2)) & 3;
    const int scg  = (tid & 3) ^ skey;
    const u16* a0p = A  + (size_t)(m0 + srow)*E_       + scg*8;
    const u16* a1p = A  + (size_t)(m0 + srow + 128)*E_ + scg*8;
    const u16* b0p = Bw + (size_t)(n0 + srow)*E_       + scg*8;
    const u16* b1p = Bw + (size_t)(n0 + srow + 128)*E_ + scg*8;
    const int d0 = tid*8, d1 = (tid + 512)*8;

    const int aoff0 = (wr*128 + fr)*32 + ((cg ^ lkey) * 8);
    const int boff0 = (wc*64  + fr)*32 + ((cg ^ lkey) * 8);

    f32x4 acc[8][4] = {};

    float bias_v[4];
#pragma unroll
    for (int nf = 0; nf < 4; ++nf) bias_v[nf] = bias[n0 + wc*64 + nf*16 + fr];

#define STAGE_G(DB, TN, STB, STKS) do { \
        u16* sd_ = lds + (DB)*32768 + ((STB) ? 16384 : 0) + (STKS)*8192; \
        const int ko_ = ((TN)&15)*BKT + (STKS)*32; \
        if (STB) { \
            __builtin_amdgcn_global_load_lds((gaddr_t)(b0p + ko_), (laddr_t)(sd_ + d0), 16, 0, 0); \
            __builtin_amdgcn_global_load_lds((gaddr_t)(b1p + ko_), (laddr_t)(sd_ + d1), 16, 0, 0); \
        } else { \
            __builtin_amdgcn_global_load_lds((gaddr_t)(a0p + ko_), (laddr_t)(sd_ + d0), 16, 0, 0); \
            __builtin_amdgcn_global_load_lds((gaddr_t)(a1p + ko_), (laddr_t)(sd_ + d1), 16, 0, 0); \
        } } while (0)

#define PHASE(CB, T, KS, MH, STB, STKS) do { \
        const u16* Ab_ = lds + (CB)*32768 + (KS)*8192; \
        const u16* Bb_ = lds + (CB)*32768 + 16384 + (KS)*8192; \
        bf16x8 bf_[4], af_[4]; \
        bf_[0] = *reinterpret_cast<const bf16x8*>(Bb_ + boff0 + 0*512); \
        bf_[1] = *reinterpret_cast<const bf16x8*>(Bb_ + boff0 + 1*512); \
        bf_[2] = *reinterpret_cast<const bf16x8*>(Bb_ + boff0 + 2*512); \
        bf_[3] = *reinterpret_cast<const bf16x8*>(Bb_ + boff0 + 3*512); \
        af_[0] = *reinterpret_cast<const bf16x8*>(Ab_ + aoff0 + ((MH)*4+0)*512); \
        af_[1] = *reinterpret_cast<const bf16x8*>(Ab_ + aoff0 + ((MH)*4+1)*512); \
        af_[2] = *reinterpret_cast<const bf16x8*>(Ab_ + aoff0 + ((MH)*4+2)*512); \
        af_[3] = *reinterpret_cast<const bf16x8*>(Ab_ + aoff0 + ((MH)*4+3)*512); \
        STAGE_G((CB)^1, (T)+1, STB, STKS); \
        if ((MH) == 1) VM_WAIT(4); \
        LG0; \
        __builtin_amdgcn_sched_barrier(0); \
        __builtin_amdgcn_s_barrier(); \
        __builtin_amdgcn_s_setprio(1); \
        _Pragma("unroll") \
        for (int i_ = 0; i_ < 4; ++i_) { \
            _Pragma("unroll") \
            for (int j_ = 0; j_ < 4; ++j_) \
                acc[(MH)*4+i_][j_] = __builtin_amdgcn_mfma_f32_16x16x32_bf16(af_[i_], bf_[j_], acc[(MH)*4+i_][j_], 0, 0, 0); \
        } \
        __builtin_amdgcn_s_setprio(0); \
    } while (0)

    STAGE_G(0, 0, 0, 0);
    STAGE_G(0, 0, 1, 0);
    STAGE_G(0, 0, 0, 1);
    STAGE_G(0, 0, 1, 1);
    VM_WAIT(0);
    __builtin_amdgcn_s_barrier();
    __builtin_amdgcn_sched_barrier(0);

#pragma unroll 1
    for (int tp = 0; tp < NKT/2; ++tp) {
        const int t0 = tp*2, t1 = tp*2 + 1;
        PHASE(0, t0, 0, 0, 0, 0);
        PHASE(0, t0, 0, 1, 1, 0);
        PHASE(0, t0, 1, 0, 0, 1);
        PHASE(0, t0, 1, 1, 1, 1);
        PHASE(1, t1, 0, 0, 0, 0);
        PHASE(1, t1, 0, 1, 1, 0);
        PHASE(1, t1, 1, 0, 0, 1);
        PHASE(1, t1, 1, 1, 1, 1);
    }
#undef PHASE
#undef STAGE_G

#pragma unroll
    for (int mf = 0; mf < 8; ++mf) {
#pragma unroll
        for (int nf = 0; nf < 4; ++nf) {
            const int gn = n0 + wc*64 + nf*16 + fr;
#pragma unroll
            for (int r = 0; r < 4; ++r) {
                const int gm = m0 + wr*128 + mf*16 + cg*4 + r;
                float x = acc[mf][nf][r] + bias_v[nf];
                if (EPI == 0) {
                    Cf[(size_t)gm*E_ + gn] = x;
                } else if (EPI == 1) {
                    x = fmaxf(x, 0.f) + kEPS;
                    Cb[(size_t)gm*E_ + gn] = f2bf(x);
                } else if (EPI == 2) {
                    x = fmaxf(x, 0.f) + kEPS;
                    if (mask[gm]) x = 0.f;
                    Cb[(size_t)gm*E_ + gn] = f2bf(x);
                } else {
                    Cb[(size_t)gm*E_ + gn] = f2bf(x);
                }
            }
        }
    }
}

// ---------------- stage 2: kv partial = K_chunk^T @ V_chunk ----------------
#define KVS 256             // s-rows per chunk
#define KVCH (S_/KVS)       // 16 chunks
#define KPAD 72             // padded row stride (u16)
__global__ __launch_bounds__(256)
void kv_partial_kernel(const u16* __restrict__ Ka, const u16* __restrict__ Vv,
                       float* __restrict__ kvp, float* __restrict__ ksp)
{
    __shared__ u16 Ks[KVS*KPAD];   // 36 KB
    __shared__ u16 Vs[KVS*KPAD];   // 36 KB
    const int bh = blockIdx.x, b = bh >> 4, h = bh & 15;
    const int s0 = blockIdx.y * KVS;
    const int tid = threadIdx.x;

#pragma unroll
    for (int i = 0; i < 8; ++i) {
        int g = i*256 + tid;
        int row = g >> 3, c8 = (g & 7) * 8;
        size_t goff = (size_t)(b*S_ + s0 + row)*E_ + h*64 + c8;
        *reinterpret_cast<uint4*>(Ks + row*KPAD + c8) = *reinterpret_cast<const uint4*>(Ka + goff);
        *reinterpret_cast<uint4*>(Vs + row*KPAD + c8) = *reinterpret_cast<const uint4*>(Vv + goff);
    }
    __syncthreads();

    const int dg = tid >> 4;
    const int vg = tid & 15;
    float acc[16] = {};
#pragma unroll 4
    for (int s = 0; s < KVS; ++s) {
        uint2 ku = *reinterpret_cast<const uint2*>(Ks + s*KPAD + dg*4);
        uint2 vu = *reinterpret_cast<const uint2*>(Vs + s*KPAD + vg*4);
        float k0 = lo2f(ku.x), k1 = hi2f(ku.x), k2 = lo2f(ku.y), k3 = hi2f(ku.y);
        float v0 = lo2f(vu.x), v1 = hi2f(vu.x), v2 = lo2f(vu.y), v3 = hi2f(vu.y);
        acc[0]  += k0*v0; acc[1]  += k0*v1; acc[2]  += k0*v2; acc[3]  += k0*v3;
        acc[4]  += k1*v0; acc[5]  += k1*v1; acc[6]  += k1*v2; acc[7]  += k1*v3;
        acc[8]  += k2*v0; acc[9]  += k2*v1; acc[10] += k2*v2; acc[11] += k2*v3;
        acc[12] += k3*v0; acc[13] += k3*v1; acc[14] += k3*v2; acc[15] += k3*v3;
    }
    float* dst = kvp + ((size_t)blockIdx.y*64 + bh)*4096;
#pragma unroll
    for (int i = 0; i < 4; ++i) {
        f32x4 o; o[0] = acc[i*4+0]; o[1] = acc[i*4+1]; o[2] = acc[i*4+2]; o[3] = acc[i*4+3];
        *reinterpret_cast<f32x4*>(dst + (dg*4+i)*64 + vg*4) = o;
    }

    __syncthreads();
    {
        const int col = tid & 63, grp = tid >> 6;
        float s = 0.f;
#pragma unroll 8
        for (int r = 0; r < 64; ++r) s += bf2f(Ks[(grp*64 + r)*KPAD + col]);
        ((float*)Vs)[grp*64 + col] = s;
    }
    __syncthreads();
    if (tid < 64) {
        const float* sc = (const float*)Vs;
        float t = sc[tid] + sc[64+tid] + sc[128+tid] + sc[192+tid];
        ksp[((size_t)blockIdx.y*64 + bh)*64 + tid] = t;
    }
}

// ---- stage 2b: reduce partials -> kvT (bf16, [v][d]) + ksum ----
// grid: 256 blocks = (bh 64) x (d-quarter 4). Thread sums 4 v-elements
// across 16 chunks with f32x4 loads (16 outstanding 16B loads), then
// transpose via padded LDS, write 32B contiguous bf16 segments.
__global__ __launch_bounds__(256)
void kv_reduce_kernel(const float* __restrict__ kvp, const float* __restrict__ ksp,
                      u16* __restrict__ kvT, float* __restrict__ ksum)
{
    __shared__ float Tt[16][68];   // padded: 2-way bank aliasing only
    const int bh = blockIdx.x >> 2, q = blockIdx.x & 3;
    const int tid = threadIdx.x;

    const size_t base = (size_t)bh*4096 + q*1024 + tid*4;
    f32x4 s = {};
#pragma unroll
    for (int c = 0; c < KVCH; ++c) {
        f32x4 x = *reinterpret_cast<const f32x4*>(kvp + (size_t)c*64*4096 + base);
        s[0] += x[0]; s[1] += x[1]; s[2] += x[2]; s[3] += x[3];
    }
    const int dq = tid >> 4, v0 = (tid & 15) * 4;
    Tt[dq][v0] = s[0]; Tt[dq][v0+1] = s[1]; Tt[dq][v0+2] = s[2]; Tt[dq][v0+3] = s[3];

    if (q == 0 && tid < 64) {
        float t = 0.f;
#pragma unroll
        for (int c = 0; c < KVCH; ++c) t += ksp[((size_t)c*64 + bh)*64 + tid];
        ksum[bh*64 + tid] = t;
    }
    __syncthreads();

    if (tid < 64) {
        const int v = tid;
        u16x8 o0, o1;
#pragma unroll
        for (int j = 0; j < 8; ++j) { o0[j] = f2bf(Tt[j][v]); o1[j] = f2bf(Tt[8+j][v]); }
        u16* dst = kvT + (size_t)bh*4096 + v*64 + q*16;
        *reinterpret_cast<u16x8*>(dst)     = o0;
        *reinterpret_cast<u16x8*>(dst + 8) = o1;
    }
}

// ---------------- stage 3: attn = (Qa @ kv) / max(Qa . ksum, eps), MFMA ----------------
__global__ __launch_bounds__(256)
void attn_kernel(const u16* __restrict__ Qa, const u16* __restrict__ kvT,
                 const float* __restrict__ ksum, u16* __restrict__ attn)
{
    __shared__ u16  Qs[256*64];
    __shared__ u16  Ts[64*64];
    __shared__ float kss[64];
    __shared__ float invd[256];

    const int bh = blockIdx.x, b = bh >> 4, h = bh & 15;
    const int s0 = blockIdx.y * 256;
    const int tid = threadIdx.x;
    const int wid = tid >> 6, lane = tid & 63;
    const int fr = lane & 15, cg = lane >> 4;

#pragma unroll
    for (int j = 0; j < 8; ++j) {
        int L = (wid*8 + j)*64 + lane;
        int row = L >> 3, c = L & 7;
        int cs = c ^ (row & 7);
        const u16* src = Qa + (size_t)(b*S_ + s0 + row)*E_ + h*64 + cs*8;
        __builtin_amdgcn_global_load_lds((gaddr_t)src, (laddr_t)(Qs + L*8), 16, 0, 0);
    }
#pragma unroll
    for (int k = 0; k < 2; ++k) {
        int g = k*256 + tid;
        int v = g >> 3, c = g & 7;
        uint4 q = *reinterpret_cast<const uint4*>(kvT + (size_t)bh*4096 + g*8);
        int cs = c ^ (v & 7);
        *reinterpret_cast<uint4*>(Ts + v*64 + cs*8) = q;
    }
    if (tid < 64) kss[tid] = ksum[bh*64 + tid];
    asm volatile("s_waitcnt vmcnt(0) lgkmcnt(0)" ::: "memory");
    __syncthreads();

    {
        float den = 0.f;
#pragma unroll
        for (int c = 0; c < 8; ++c) {
            uint4 qc = *reinterpret_cast<const uint4*>(Qs + tid*64 + (c ^ (tid & 7))*8);
            den += lo2f(qc.x)*kss[c*8+0] + hi2f(qc.x)*kss[c*8+1]
                 + lo2f(qc.y)*kss[c*8+2] + hi2f(qc.y)*kss[c*8+3]
                 + lo2f(qc.z)*kss[c*8+4] + hi2f(qc.z)*kss[c*8+5]
                 + lo2f(qc.w)*kss[c*8+6] + hi2f(qc.w)*kss[c*8+7];
        }
        invd[tid] = 1.0f / fmaxf(den, kEPS);
    }
    __syncthreads();

    f32x4 acc[4][4] = {};
#pragma unroll
    for (int ks = 0; ks < 2; ++ks) {
        bf16x8 bfrag[4];
#pragma unroll
        for (int nf = 0; nf < 4; ++nf) {
            int v = nf*16 + fr;
            bfrag[nf] = *reinterpret_cast<const bf16x8*>(Ts + v*64 + ((ks*4 + cg) ^ (v & 7))*8);
        }
#pragma unroll
        for (int mf = 0; mf < 4; ++mf) {
            int m = wid*64 + mf*16 + fr;
            bf16x8 afrag = *reinterpret_cast<const bf16x8*>(Qs + m*64 + ((ks*4 + cg) ^ (m & 7))*8);
#pragma unroll
            for (int nf = 0; nf < 4; ++nf)
                acc[mf][nf] = __builtin_amdgcn_mfma_f32_16x16x32_bf16(afrag, bfrag[nf], acc[mf][nf], 0, 0, 0);
        }
    }

#pragma unroll
    for (int mf = 0; mf < 4; ++mf) {
#pragma unroll
        for (int nf = 0; nf < 4; ++nf) {
            const int v = nf*16 + fr;
#pragma unroll
            for (int r = 0; r < 4; ++r) {
                const int row = wid*64 + mf*16 + cg*4 + r;
                float x = acc[mf][nf][r] * invd[row];
                attn[(size_t)(b*S_ + s0 + row)*E_ + h*64 + v] = f2bf(x);
            }
        }
    }
}

// ---------------- host ----------------
extern "C" void kernel_launch(void* const* d_in, const int* in_sizes, int n_in,
                              void* d_out, int out_size, void* d_ws, size_t ws_size,
                              hipStream_t stream)
{
    const float* query = (const float*)d_in[0];
    const float* key   = (const float*)d_in[1];
    const float* value = (const float*)d_in[2];
    const u8*    mask  = (const u8*)d_in[3];
    const float* Wq = (const float*)d_in[4];
    const float* bq = (const float*)d_in[5];
    const float* Wk = (const float*)d_in[6];
    const float* bk = (const float*)d_in[7];
    const float* Wv = (const float*)d_in[8];
    const float* bv = (const float*)d_in[9];
    const float* Wo = (const float*)d_in[10];
    const float* bo = (const float*)d_in[11];
    float* out = (float*)d_out;

    const size_t SZ_ME = (size_t)M_ * E_;
    const size_t SZ_EE = (size_t)E_ * E_;

    char* ws = (char*)d_ws;
    u16* qx   = (u16*)ws; ws += SZ_ME*2;   // query bf16; reused for attnb
    u16* kx   = (u16*)ws; ws += SZ_ME*2;   // key bf16; reused for kvp
    u16* vx   = (u16*)ws; ws += SZ_ME*2;   // value bf16; reused for ksp/kvT/ksum
    u16* Qa   = (u16*)ws; ws += SZ_ME*2;
    u16* Ka   = (u16*)ws; ws += SZ_ME*2;
    u16* Vv   = (u16*)ws; ws += SZ_ME*2;
    u16* wqb  = (u16*)ws; ws += SZ_EE*2;
    u16* wkb  = (u16*)ws; ws += SZ_EE*2;
    u16* wvb  = (u16*)ws; ws += SZ_EE*2;
    u16* wob  = (u16*)ws; ws += SZ_EE*2;

    // overlays (dead by the time they're written)
    u16*   attnb = qx;
    float* kvp   = (float*)kx;                                        // 16 MiB
    float* ksp   = (float*)vx;                                        // 256 KiB
    u16*   kvT   = (u16*)((char*)vx + (size_t)KVCH*64*64*4);          // 512 KiB
    float* ksum  = (float*)((char*)kvT + (size_t)64*4096*2);

    // 1) conversions to bf16
    cvt_kernel<<<(int)(SZ_ME/4/256), 256, 0, stream>>>(query, qx, (int)(SZ_ME/4));
    cvt_kernel<<<(int)(SZ_ME/4/256), 256, 0, stream>>>(key,   kx, (int)(SZ_ME/4));
    cvt_kernel<<<(int)(SZ_ME/4/256), 256, 0, stream>>>(value, vx, (int)(SZ_ME/4));
    cvt_kernel<<<(int)(SZ_EE/4/256), 256, 0, stream>>>(Wq, wqb, (int)(SZ_EE/4));
    cvt_kernel<<<(int)(SZ_EE/4/256), 256, 0, stream>>>(Wk, wkb, (int)(SZ_EE/4));
    cvt_kernel<<<(int)(SZ_EE/4/256), 256, 0, stream>>>(Wv, wvb, (int)(SZ_EE/4));
    cvt_kernel<<<(int)(SZ_EE/4/256), 256, 0, stream>>>(Wo, wob, (int)(SZ_EE/4));

    // 2) QKV projections (8-phase GEMM)
    dim3 ggrid(M_/BM, E_/BN);
    constexpr size_t LDS_BYTES = 2 * 32768 * sizeof(u16);   // 128 KB
    gemm8<1><<<ggrid, 512, LDS_BYTES, stream>>>(qx, wqb, bq, nullptr, nullptr, Qa);
    gemm8<2><<<ggrid, 512, LDS_BYTES, stream>>>(kx, wkb, bk, mask,    nullptr, Ka);
    gemm8<3><<<ggrid, 512, LDS_BYTES, stream>>>(vx, wvb, bv, nullptr, nullptr, Vv);

    // 3) kv_context + k_sum (two-phase, deterministic)
    kv_partial_kernel<<<dim3(B_*H_, KVCH), 256, 0, stream>>>(Ka, Vv, kvp, ksp);
    kv_reduce_kernel<<<256, 256, 0, stream>>>(kvp, ksp, kvT, ksum);

    // 4) attn numerator / denom (MFMA)
    attn_kernel<<<dim3(B_*H_, S_/256), 256, 0, stream>>>(Qa, kvT, ksum, attnb);

    // 5) output projection -> f32 out
    gemm8<0><<<ggrid, 512, LDS_BYTES, stream>>>(attnb, wob, bo, nullptr, out, nullptr);
}

// Round 6
// 284.134 us; speedup vs baseline: 1.2393x; 1.0548x over previous
//
#include <hip/hip_runtime.h>
#include <hip/hip_bf16.h>
#include <stdint.h>

#define B_ 4
#define S_ 4096
#define E_ 1024
#define H_ 16
#define D_ 64
#define M_ (B_*S_)          // 16384 rows
constexpr float kEPS = 1e-6f;

typedef unsigned short u16;
typedef unsigned char  u8;
typedef __bf16 bf16x8 __attribute__((ext_vector_type(8)));
typedef float  f32x4  __attribute__((ext_vector_type(4)));
typedef float  f32x2  __attribute__((ext_vector_type(2)));
typedef u16    u16x8  __attribute__((ext_vector_type(8)));

typedef const __attribute__((address_space(1))) void* gaddr_t;
typedef __attribute__((address_space(3))) void*       laddr_t;

__device__ __forceinline__ u16 f2bf(float f) {
    union { float f; uint32_t u; } v; v.f = f;
    uint32_t u = v.u;
    u += 0x7fffu + ((u >> 16) & 1u);   // RNE
    return (u16)(u >> 16);
}
__device__ __forceinline__ float bf2f(u16 h) {
    union { uint32_t u; float f; } v; v.u = ((uint32_t)h) << 16;
    return v.f;
}
__device__ __forceinline__ float hi2f(uint32_t d) {
    union { uint32_t u; float f; } v; v.u = d & 0xffff0000u;
    return v.f;
}
__device__ __forceinline__ float lo2f(uint32_t d) {
    union { uint32_t u; float f; } v; v.u = d << 16;
    return v.f;
}

#define VM_WAIT(n) asm volatile("s_waitcnt vmcnt(" #n ")" ::: "memory")
#define LG0        asm volatile("s_waitcnt lgkmcnt(0)" ::: "memory")
#define SBAR       asm volatile("s_barrier" ::: "memory")

// ---------------- f32 -> bf16 conversion ----------------
__global__ void cvt_kernel(const float* __restrict__ in, u16* __restrict__ out, int n4) {
    int i = blockIdx.x * blockDim.x + threadIdx.x;
    if (i >= n4) return;
    float4 v = reinterpret_cast<const float4*>(in)[i];
    ushort4 o;
    o.x = f2bf(v.x); o.y = f2bf(v.y); o.z = f2bf(v.z); o.w = f2bf(v.w);
    reinterpret_cast<ushort4*>(out)[i] = o;
}

// ================= m201-style 8-phase 256x256 GEMM, C = A @ W^T =================
// Phase = one C-quadrant (mh,nh), ALL 8 waves cooperate; full K=64 per phase.
// 2 LDS buffers x (A[256][64] + B[256][64]) bf16 = 128 KB.
// Per phase: ds_reads + stage ONE half-tile (16KB, 2 gload_lds) into the region
// freed one phase earlier; vmcnt(4) only at phases 4 and 8; 2 barriers/phase.
#define BM 256
#define BN 256
#define BKT 64
#define NKT (E_/BKT)        // 16 K-tiles
// LDS u16 offsets: buf*32768; A-half h at h*8192; B at 16384 + h*8192.

template<int EPI>
__global__ __launch_bounds__(512, 2)
void gemm8(const u16* __restrict__ A, const u16* __restrict__ Bw,
           const float* __restrict__ bias, const u8* __restrict__ mask,
           float* __restrict__ Cf, u16* __restrict__ Cb)
{
    extern __shared__ u16 lds[];   // 65536 u16 = 128 KB
    const int tid  = threadIdx.x;
    const int wid  = tid >> 6, lane = tid & 63;
    const int wqr  = wid >> 2, wqc = wid & 3;     // wave pos inside a 128x128 quadrant
    const int m0   = blockIdx.x * BM;
    const int n0   = blockIdx.y * BN;
    const int fr   = lane & 15;
    const int cg   = lane >> 4;

    // ---- staging geometry: half = 128 rows x 64 k = 1024 slots of 16B; 2 loads/thread
    const int srow = tid >> 3;                    // 0..63 (load1 adds +64 rows)
    const int ssc  = tid & 7;
    const int sck  = ssc ^ (srow & 7);            // stored chunk sc holds content ck = sc ^ (row&7)
    const u16* aS = A  + (size_t)(m0 + srow)*E_ + sck*8;
    const u16* bS = Bw + (size_t)(n0 + srow)*E_ + sck*8;
    const int sd0 = tid*8, sd1 = (tid + 512)*8;   // u16 offsets within an 8192-u16 half region

    // ---- fragment read offsets (u16, within a half region) ----
    int arow[4], brow[2];
#pragma unroll
    for (int mf = 0; mf < 4; ++mf) arow[mf] = (wqr*64 + mf*16 + fr) * 64;
#pragma unroll
    for (int nf = 0; nf < 2; ++nf) brow[nf] = (wqc*32 + nf*16 + fr) * 64;
    const int kx0 = ((cg)     ^ (fr & 7)) * 8;
    const int kx1 = ((4 + cg) ^ (fr & 7)) * 8;

    f32x4 acc[2][2][4][2] = {};
    bf16x8 afr[4][2];

    float bias_v[2][2];
#pragma unroll
    for (int nh = 0; nh < 2; ++nh)
#pragma unroll
        for (int nf = 0; nf < 2; ++nf)
            bias_v[nh][nf] = bias[n0 + nh*128 + wqc*32 + nf*16 + fr];

    // stage half H of matrix MAT (0=A,1=B) of tile T into buffer BUF
#define STAGE(BUF, MAT, H, T) do { \
        u16* dst_ = lds + (BUF)*32768 + (MAT)*16384 + (H)*8192; \
        const u16* src_ = ((MAT) ? bS : aS) + (size_t)(H)*128*E_ + (size_t)(T)*BKT; \
        __builtin_amdgcn_global_load_lds((gaddr_t)(src_),                  (laddr_t)(dst_ + sd0), 16, 0, 0); \
        __builtin_amdgcn_global_load_lds((gaddr_t)(src_ + (size_t)64*E_), (laddr_t)(dst_ + sd1), 16, 0, 0); \
    } while (0)

    // one phase: quadrant (MH,NH) of the tile in buffer BUF
#define PH(BUF, MH, NH, STG_STMT, WAIT_STMT) do { \
        const u16* Ab_ = lds + (BUF)*32768 + (MH)*8192; \
        const u16* Bb_ = lds + (BUF)*32768 + 16384 + (NH)*8192; \
        if ((NH) == 0) { \
            _Pragma("unroll") \
            for (int mf_ = 0; mf_ < 4; ++mf_) { \
                afr[mf_][0] = *reinterpret_cast<const bf16x8*>(Ab_ + arow[mf_] + kx0); \
                afr[mf_][1] = *reinterpret_cast<const bf16x8*>(Ab_ + arow[mf_] + kx1); \
            } \
        } \
        bf16x8 bfv[2][2]; \
        _Pragma("unroll") \
        for (int nf_ = 0; nf_ < 2; ++nf_) { \
            bfv[nf_][0] = *reinterpret_cast<const bf16x8*>(Bb_ + brow[nf_] + kx0); \
            bfv[nf_][1] = *reinterpret_cast<const bf16x8*>(Bb_ + brow[nf_] + kx1); \
        } \
        STG_STMT; \
        WAIT_STMT; \
        SBAR; \
        LG0; \
        __builtin_amdgcn_sched_barrier(0); \
        __builtin_amdgcn_s_setprio(1); \
        _Pragma("unroll") \
        for (int mf_ = 0; mf_ < 4; ++mf_) { \
            _Pragma("unroll") \
            for (int nf_ = 0; nf_ < 2; ++nf_) { \
                acc[MH][NH][mf_][nf_] = __builtin_amdgcn_mfma_f32_16x16x32_bf16(afr[mf_][0], bfv[nf_][0], acc[MH][NH][mf_][nf_], 0, 0, 0); \
                acc[MH][NH][mf_][nf_] = __builtin_amdgcn_mfma_f32_16x16x32_bf16(afr[mf_][1], bfv[nf_][1], acc[MH][NH][mf_][nf_], 0, 0, 0); \
            } \
        } \
        __builtin_amdgcn_s_setprio(0); \
        SBAR; \
    } while (0)

    // prologue: tile0 fully into buf0, tile1 halves A0,B0 into buf1
    STAGE(0, 0, 0, 0);
    STAGE(0, 1, 0, 0);
    STAGE(0, 0, 1, 0);
    STAGE(0, 1, 1, 0);
    STAGE(1, 0, 0, 1);
    STAGE(1, 1, 0, 1);
    VM_WAIT(4);
    SBAR;
    __builtin_amdgcn_sched_barrier(0);

#pragma unroll 1
    for (int i = 0; i < 7; ++i) {
        const int T1 = 2*i + 1, T2 = 2*i + 2, T3 = 2*i + 3;
        PH(0, 0, 0, STAGE(1, 0, 1, T1), ;);            // ph1
        PH(0, 0, 1, STAGE(1, 1, 1, T1), ;);            // ph2
        PH(0, 1, 0, STAGE(0, 0, 0, T2), ;);            // ph3
        PH(0, 1, 1, STAGE(0, 1, 0, T2), VM_WAIT(4));   // ph4
        PH(1, 0, 0, STAGE(0, 0, 1, T2), ;);            // ph5
        PH(1, 0, 1, STAGE(0, 1, 1, T2), ;);            // ph6
        PH(1, 1, 0, STAGE(1, 0, 0, T3), ;);            // ph7
        PH(1, 1, 1, STAGE(1, 1, 0, T3), VM_WAIT(4));   // ph8
    }
    // peeled last iteration: tiles 14,15; only A1,B1(15) still to stage
    PH(0, 0, 0, STAGE(1, 0, 1, 15), ;);
    PH(0, 0, 1, STAGE(1, 1, 1, 15), ;);
    PH(0, 1, 0, ;, ;);
    PH(0, 1, 1, ;, VM_WAIT(0));
    PH(1, 0, 0, ;, ;);
    PH(1, 0, 1, ;, ;);
    PH(1, 1, 0, ;, ;);
    PH(1, 1, 1, ;, ;);
#undef PH
#undef STAGE

    // ---- epilogue ----
#pragma unroll
    for (int mh = 0; mh < 2; ++mh) {
#pragma unroll
    for (int nh = 0; nh < 2; ++nh) {
#pragma unroll
    for (int mf = 0; mf < 4; ++mf) {
#pragma unroll
        for (int nf = 0; nf < 2; ++nf) {
            const int gn = n0 + nh*128 + wqc*32 + nf*16 + fr;
#pragma unroll
            for (int r = 0; r < 4; ++r) {
                const int gm = m0 + mh*128 + wqr*64 + mf*16 + cg*4 + r;
                float x = acc[mh][nh][mf][nf][r] + bias_v[nh][nf];
                if (EPI == 0) {
                    Cf[(size_t)gm*E_ + gn] = x;
                } else if (EPI == 1) {
                    x = fmaxf(x, 0.f) + kEPS;
                    Cb[(size_t)gm*E_ + gn] = f2bf(x);
                } else if (EPI == 2) {
                    x = fmaxf(x, 0.f) + kEPS;
                    if (mask[gm]) x = 0.f;
                    Cb[(size_t)gm*E_ + gn] = f2bf(x);
                } else {
                    Cb[(size_t)gm*E_ + gn] = f2bf(x);
                }
            }
        }
    }
    }
    }
}

// ---------------- stage 2: kv partial = K_chunk^T @ V_chunk (f32 LDS, pk-fma) ----------------
#define KVS 128             // s-rows per chunk
#define KVCH (S_/KVS)       // 32 chunks
#define KPF 66              // padded f32 row stride
__global__ __launch_bounds__(256)
void kv_partial_kernel(const u16* __restrict__ Ka, const u16* __restrict__ Vv,
                       float* __restrict__ kvp, float* __restrict__ ksp)
{
    __shared__ float Ksf[KVS*KPF];   // 33 KB
    __shared__ float Vsf[KVS*KPF];   // 33 KB
    const int bh = blockIdx.x, b = bh >> 4, h = bh & 15;
    const int s0 = blockIdx.y * KVS;
    const int tid = threadIdx.x;

#pragma unroll
    for (int i = 0; i < 4; ++i) {           // 1024 chunk-slots per matrix
        int g = i*256 + tid;
        int row = g >> 3, c8 = (g & 7) * 8;
        size_t goff = (size_t)(b*S_ + s0 + row)*E_ + h*64 + c8;
        bf16x8 kk = *reinterpret_cast<const bf16x8*>(Ka + goff);
        bf16x8 vv = *reinterpret_cast<const bf16x8*>(Vv + goff);
        f32x4 k0, k1, v0, v1;
#pragma unroll
        for (int j = 0; j < 4; ++j) {
            k0[j] = (float)kk[j]; k1[j] = (float)kk[4+j];
            v0[j] = (float)vv[j]; v1[j] = (float)vv[4+j];
        }
        *reinterpret_cast<f32x4*>(Ksf + row*KPF + c8)     = k0;
        *reinterpret_cast<f32x4*>(Ksf + row*KPF + c8 + 4) = k1;
        *reinterpret_cast<f32x4*>(Vsf + row*KPF + c8)     = v0;
        *reinterpret_cast<f32x4*>(Vsf + row*KPF + c8 + 4) = v1;
    }
    __syncthreads();

    const int dg = tid >> 4;       // d0 = dg*4
    const int vg = tid & 15;       // v0 = vg*4
    f32x2 acc2[4][2] = {};
#pragma unroll 4
    for (int s = 0; s < KVS; ++s) {
        f32x4 k4 = *reinterpret_cast<const f32x4*>(Ksf + s*KPF + dg*4);
        f32x4 v4 = *reinterpret_cast<const f32x4*>(Vsf + s*KPF + vg*4);
        f32x2 va; va[0] = v4[0]; va[1] = v4[1];
        f32x2 vb; vb[0] = v4[2]; vb[1] = v4[3];
#pragma unroll
        for (int d = 0; d < 4; ++d) {
            f32x2 kd; kd[0] = k4[d]; kd[1] = k4[d];
            acc2[d][0] += kd * va;
            acc2[d][1] += kd * vb;
        }
    }
    float* dst = kvp + ((size_t)blockIdx.y*64 + bh)*4096;
#pragma unroll
    for (int d = 0; d < 4; ++d) {
        f32x4 o; o[0] = acc2[d][0][0]; o[1] = acc2[d][0][1]; o[2] = acc2[d][1][0]; o[3] = acc2[d][1][1];
        *reinterpret_cast<f32x4*>(dst + (dg*4 + d)*64 + vg*4) = o;
    }

    // ksum partial: column sums of Ksf
    __syncthreads();                 // all Vsf reads done -> reuse as scratch
    {
        const int col = tid & 63, grp = tid >> 6;
        float s = 0.f;
#pragma unroll 8
        for (int r = 0; r < KVS/4; ++r) s += Ksf[(grp*(KVS/4) + r)*KPF + col];
        Vsf[grp*64 + col] = s;
    }
    __syncthreads();
    if (tid < 64) {
        ksp[((size_t)blockIdx.y*64 + bh)*64 + tid] =
            Vsf[tid] + Vsf[64+tid] + Vsf[128+tid] + Vsf[192+tid];
    }
}

// ---- stage 2b: reduce partials -> kvT (bf16, [v][d]) + ksum ----
__global__ __launch_bounds__(256)
void kv_reduce_kernel(const float* __restrict__ kvp, const float* __restrict__ ksp,
                      u16* __restrict__ kvT, float* __restrict__ ksum)
{
    __shared__ float Tt[16][68];
    const int bh = blockIdx.x >> 2, q = blockIdx.x & 3;
    const int tid = threadIdx.x;

    const size_t base = (size_t)bh*4096 + q*1024 + tid*4;
    f32x4 s = {};
#pragma unroll 8
    for (int c = 0; c < KVCH; ++c) {
        f32x4 x = *reinterpret_cast<const f32x4*>(kvp + (size_t)c*64*4096 + base);
        s[0] += x[0]; s[1] += x[1]; s[2] += x[2]; s[3] += x[3];
    }
    const int dq = tid >> 4, v0 = (tid & 15) * 4;
    Tt[dq][v0] = s[0]; Tt[dq][v0+1] = s[1]; Tt[dq][v0+2] = s[2]; Tt[dq][v0+3] = s[3];

    if (q == 0 && tid < 64) {
        float t = 0.f;
#pragma unroll 8
        for (int c = 0; c < KVCH; ++c) t += ksp[((size_t)c*64 + bh)*64 + tid];
        ksum[bh*64 + tid] = t;
    }
    __syncthreads();

    if (tid < 64) {
        const int v = tid;
        u16x8 o0, o1;
#pragma unroll
        for (int j = 0; j < 8; ++j) { o0[j] = f2bf(Tt[j][v]); o1[j] = f2bf(Tt[8+j][v]); }
        u16* dst = kvT + (size_t)bh*4096 + v*64 + q*16;
        *reinterpret_cast<u16x8*>(dst)     = o0;
        *reinterpret_cast<u16x8*>(dst + 8) = o1;
    }
}

// ---------------- stage 3: attn = (Qa @ kv) / max(Qa . ksum, eps), MFMA ----------------
__global__ __launch_bounds__(256)
void attn_kernel(const u16* __restrict__ Qa, const u16* __restrict__ kvT,
                 const float* __restrict__ ksum, u16* __restrict__ attn)
{
    __shared__ u16  Qs[256*64];
    __shared__ u16  Ts[64*64];
    __shared__ float kss[64];
    __shared__ float invd[256];

    const int bh = blockIdx.x, b = bh >> 4, h = bh & 15;
    const int s0 = blockIdx.y * 256;
    const int tid = threadIdx.x;
    const int wid = tid >> 6, lane = tid & 63;
    const int fr = lane & 15, cg = lane >> 4;

#pragma unroll
    for (int j = 0; j < 8; ++j) {
        int L = (wid*8 + j)*64 + lane;
        int row = L >> 3, c = L & 7;
        int cs = c ^ (row & 7);
        const u16* src = Qa + (size_t)(b*S_ + s0 + row)*E_ + h*64 + cs*8;
        __builtin_amdgcn_global_load_lds((gaddr_t)src, (laddr_t)(Qs + L*8), 16, 0, 0);
    }
#pragma unroll
    for (int k = 0; k < 2; ++k) {
        int g = k*256 + tid;
        int v = g >> 3, c = g & 7;
        uint4 q = *reinterpret_cast<const uint4*>(kvT + (size_t)bh*4096 + g*8);
        int cs = c ^ (v & 7);
        *reinterpret_cast<uint4*>(Ts + v*64 + cs*8) = q;
    }
    if (tid < 64) kss[tid] = ksum[bh*64 + tid];
    asm volatile("s_waitcnt vmcnt(0) lgkmcnt(0)" ::: "memory");
    __syncthreads();

    {
        float den = 0.f;
#pragma unroll
        for (int c = 0; c < 8; ++c) {
            uint4 qc = *reinterpret_cast<const uint4*>(Qs + tid*64 + (c ^ (tid & 7))*8);
            den += lo2f(qc.x)*kss[c*8+0] + hi2f(qc.x)*kss[c*8+1]
                 + lo2f(qc.y)*kss[c*8+2] + hi2f(qc.y)*kss[c*8+3]
                 + lo2f(qc.z)*kss[c*8+4] + hi2f(qc.z)*kss[c*8+5]
                 + lo2f(qc.w)*kss[c*8+6] + hi2f(qc.w)*kss[c*8+7];
        }
        invd[tid] = 1.0f / fmaxf(den, kEPS);
    }
    __syncthreads();

    f32x4 acc[4][4] = {};
#pragma unroll
    for (int ks = 0; ks < 2; ++ks) {
        bf16x8 bfrag[4];
#pragma unroll
        for (int nf = 0; nf < 4; ++nf) {
            int v = nf*16 + fr;
            bfrag[nf] = *reinterpret_cast<const bf16x8*>(Ts + v*64 + ((ks*4 + cg) ^ (v & 7))*8);
        }
#pragma unroll
        for (int mf = 0; mf < 4; ++mf) {
            int m = wid*64 + mf*16 + fr;
            bf16x8 afrag = *reinterpret_cast<const bf16x8*>(Qs + m*64 + ((ks*4 + cg) ^ (m & 7))*8);
#pragma unroll
            for (int nf = 0; nf < 4; ++nf)
                acc[mf][nf] = __builtin_amdgcn_mfma_f32_16x16x32_bf16(afrag, bfrag[nf], acc[mf][nf], 0, 0, 0);
        }
    }

#pragma unroll
    for (int mf = 0; mf < 4; ++mf) {
#pragma unroll
        for (int nf = 0; nf < 4; ++nf) {
            const int v = nf*16 + fr;
#pragma unroll
            for (int r = 0; r < 4; ++r) {
                const int row = wid*64 + mf*16 + cg*4 + r;
                float x = acc[mf][nf][r] * invd[row];
                attn[(size_t)(b*S_ + s0 + row)*E_ + h*64 + v] = f2bf(x);
            }
        }
    }
}

// ---------------- host ----------------
extern "C" void kernel_launch(void* const* d_in, const int* in_sizes, int n_in,
                              void* d_out, int out_size, void* d_ws, size_t ws_size,
                              hipStream_t stream)
{
    const float* query = (const float*)d_in[0];
    const float* key   = (const float*)d_in[1];
    const float* value = (const float*)d_in[2];
    const u8*    mask  = (const u8*)d_in[3];
    const float* Wq = (const float*)d_in[4];
    const float* bq = (const float*)d_in[5];
    const float* Wk = (const float*)d_in[6];
    const float* bk = (const float*)d_in[7];
    const float* Wv = (const float*)d_in[8];
    const float* bv = (const float*)d_in[9];
    const float* Wo = (const float*)d_in[10];
    const float* bo = (const float*)d_in[11];
    float* out = (float*)d_out;

    const size_t SZ_ME = (size_t)M_ * E_;
    const size_t SZ_EE = (size_t)E_ * E_;

    char* ws = (char*)d_ws;
    u16* qx   = (u16*)ws; ws += SZ_ME*2;   // query bf16; reused for attnb
    u16* kx   = (u16*)ws; ws += SZ_ME*2;   // key bf16; reused for kvp (32 MiB)
    u16* vx   = (u16*)ws; ws += SZ_ME*2;   // value bf16; reused for ksp/kvT/ksum
    u16* Qa   = (u16*)ws; ws += SZ_ME*2;
    u16* Ka   = (u16*)ws; ws += SZ_ME*2;
    u16* Vv   = (u16*)ws; ws += SZ_ME*2;
    u16* wqb  = (u16*)ws; ws += SZ_EE*2;
    u16* wkb  = (u16*)ws; ws += SZ_EE*2;
    u16* wvb  = (u16*)ws; ws += SZ_EE*2;
    u16* wob  = (u16*)ws; ws += SZ_EE*2;

    // overlays (dead by the time they're written)
    u16*   attnb = qx;
    float* kvp   = (float*)kx;                                        // 32 MiB
    float* ksp   = (float*)vx;                                        // 512 KiB
    u16*   kvT   = (u16*)((char*)vx + (size_t)KVCH*64*64*4);          // 512 KiB
    float* ksum  = (float*)((char*)kvT + (size_t)64*4096*2);

    // 1) conversions to bf16
    cvt_kernel<<<(int)(SZ_ME/4/256), 256, 0, stream>>>(query, qx, (int)(SZ_ME/4));
    cvt_kernel<<<(int)(SZ_ME/4/256), 256, 0, stream>>>(key,   kx, (int)(SZ_ME/4));
    cvt_kernel<<<(int)(SZ_ME/4/256), 256, 0, stream>>>(value, vx, (int)(SZ_ME/4));
    cvt_kernel<<<(int)(SZ_EE/4/256), 256, 0, stream>>>(Wq, wqb, (int)(SZ_EE/4));
    cvt_kernel<<<(int)(SZ_EE/4/256), 256, 0, stream>>>(Wk, wkb, (int)(SZ_EE/4));
    cvt_kernel<<<(int)(SZ_EE/4/256), 256, 0, stream>>>(Wv, wvb, (int)(SZ_EE/4));
    cvt_kernel<<<(int)(SZ_EE/4/256), 256, 0, stream>>>(Wo, wob, (int)(SZ_EE/4));

    // 2) QKV projections (8-phase GEMM)
    dim3 ggrid(M_/BM, E_/BN);
    constexpr size_t LDS_BYTES = 2 * 32768 * sizeof(u16);   // 128 KB
    gemm8<1><<<ggrid, 512, LDS_BYTES, stream>>>(qx, wqb, bq, nullptr, nullptr, Qa);
    gemm8<2><<<ggrid, 512, LDS_BYTES, stream>>>(kx, wkb, bk, mask,    nullptr, Ka);
    gemm8<3><<<ggrid, 512, LDS_BYTES, stream>>>(vx, wvb, bv, nullptr, nullptr, Vv);

    // 3) kv_context + k_sum (two-phase, deterministic)
    kv_partial_kernel<<<dim3(B_*H_, KVCH), 256, 0, stream>>>(Ka, Vv, kvp, ksp);
    kv_reduce_kernel<<<256, 256, 0, stream>>>(kvp, ksp, kvT, ksum);

    // 4) attn numerator / denom (MFMA)
    attn_kernel<<<dim3(B_*H_, S_/256), 256, 0, stream>>>(Qa, kvT, ksum, attnb);

    // 5) output projection -> f32 out
    gemm8<0><<<ggrid, 512, LDS_BYTES, stream>>>(attnb, wob, bo, nullptr, out, nullptr);
}

// Round 7
// 266.691 us; speedup vs baseline: 1.3203x; 1.0654x over previous
//
#include <hip/hip_runtime.h>
#include <hip/hip_bf16.h>
#include <stdint.h>

#define B_ 4
#define S_ 4096
#define E_ 1024
#define H_ 16
#define D_ 64
#define M_ (B_*S_)          // 16384 rows
constexpr float kEPS = 1e-6f;

typedef unsigned short u16;
typedef unsigned char  u8;
typedef __bf16 bf16x8 __attribute__((ext_vector_type(8)));
typedef float  f32x4  __attribute__((ext_vector_type(4)));
typedef u16    u16x8  __attribute__((ext_vector_type(8)));

typedef const __attribute__((address_space(1))) void* gaddr_t;
typedef __attribute__((address_space(3))) void*       laddr_t;

__device__ __forceinline__ u16 f2bf(float f) {
    union { float f; uint32_t u; } v; v.f = f;
    uint32_t u = v.u;
    u += 0x7fffu + ((u >> 16) & 1u);   // RNE
    return (u16)(u >> 16);
}
__device__ __forceinline__ float hi2f(uint32_t d) {
    union { uint32_t u; float f; } v; v.u = d & 0xffff0000u;
    return v.f;
}
__device__ __forceinline__ float lo2f(uint32_t d) {
    union { uint32_t u; float f; } v; v.u = d << 16;
    return v.f;
}

#define VM_WAIT(n) asm volatile("s_waitcnt vmcnt(" #n ")" ::: "memory")
#define LG0        asm volatile("s_waitcnt lgkmcnt(0)" ::: "memory")
#define SBAR       asm volatile("s_barrier" ::: "memory")

// ---------------- f32 -> bf16 conversion ----------------
__global__ void cvt_kernel(const float* __restrict__ in, u16* __restrict__ out, int n4) {
    int i = blockIdx.x * blockDim.x + threadIdx.x;
    if (i >= n4) return;
    float4 v = reinterpret_cast<const float4*>(in)[i];
    ushort4 o;
    o.x = f2bf(v.x); o.y = f2bf(v.y); o.z = f2bf(v.z); o.w = f2bf(v.w);
    reinterpret_cast<ushort4*>(out)[i] = o;
}

// ================= m201-style 8-phase 256x256 GEMM, C = A @ W^T =================
// EPI: 0 = f32 out + bias (natural layout)
//      1 = relu(x+b)+eps -> bf16 (natural layout)
//      2 = relu(x+b)+eps, mask-zero -> bf16 TRANSPOSED  KaT[b*1024+e][s]
//      3 = x+b -> bf16 TRANSPOSED                        VvT[b*1024+e][s]
#define BM 256
#define BN 256
#define BKT 64
#define NKT (E_/BKT)        // 16 K-tiles

template<int EPI>
__global__ __launch_bounds__(512, 2)
void gemm8(const u16* __restrict__ A, const u16* __restrict__ Bw,
           const float* __restrict__ bias, const u8* __restrict__ mask,
           float* __restrict__ Cf, u16* __restrict__ Cb)
{
    extern __shared__ u16 lds[];   // 65536 u16 = 128 KB
    const int tid  = threadIdx.x;
    const int wid  = tid >> 6, lane = tid & 63;
    const int wqr  = wid >> 2, wqc = wid & 3;     // wave pos inside a 128x128 quadrant
    const int m0   = blockIdx.x * BM;
    const int n0   = blockIdx.y * BN;
    const int fr   = lane & 15;
    const int cg   = lane >> 4;

    // ---- staging geometry: half = 128 rows x 64 k = 1024 slots of 16B; 2 loads/thread
    const int srow = tid >> 3;                    // 0..63 (load1 adds +64 rows)
    const int ssc  = tid & 7;
    const int sck  = ssc ^ (srow & 7);            // stored chunk sc holds content ck = sc ^ (row&7)
    const u16* aS = A  + (size_t)(m0 + srow)*E_ + sck*8;
    const u16* bS = Bw + (size_t)(n0 + srow)*E_ + sck*8;
    const int sd0 = tid*8, sd1 = (tid + 512)*8;   // u16 offsets within an 8192-u16 half region

    // ---- fragment read offsets (u16, within a half region) ----
    int arow[4], brow[2];
#pragma unroll
    for (int mf = 0; mf < 4; ++mf) arow[mf] = (wqr*64 + mf*16 + fr) * 64;
#pragma unroll
    for (int nf = 0; nf < 2; ++nf) brow[nf] = (wqc*32 + nf*16 + fr) * 64;
    const int kx0 = ((cg)     ^ (fr & 7)) * 8;
    const int kx1 = ((4 + cg) ^ (fr & 7)) * 8;

    f32x4 acc[2][2][4][2] = {};
    bf16x8 afr[4][2];

    float bias_v[2][2];
#pragma unroll
    for (int nh = 0; nh < 2; ++nh)
#pragma unroll
        for (int nf = 0; nf < 2; ++nf)
            bias_v[nh][nf] = bias[n0 + nh*128 + wqc*32 + nf*16 + fr];

#define STAGE(BUF, MAT, H, T) do { \
        u16* dst_ = lds + (BUF)*32768 + (MAT)*16384 + (H)*8192; \
        const u16* src_ = ((MAT) ? bS : aS) + (size_t)(H)*128*E_ + (size_t)(T)*BKT; \
        __builtin_amdgcn_global_load_lds((gaddr_t)(src_),                  (laddr_t)(dst_ + sd0), 16, 0, 0); \
        __builtin_amdgcn_global_load_lds((gaddr_t)(src_ + (size_t)64*E_), (laddr_t)(dst_ + sd1), 16, 0, 0); \
    } while (0)

#define PH(BUF, MH, NH, STG_STMT, WAIT_STMT) do { \
        const u16* Ab_ = lds + (BUF)*32768 + (MH)*8192; \
        const u16* Bb_ = lds + (BUF)*32768 + 16384 + (NH)*8192; \
        if ((NH) == 0) { \
            _Pragma("unroll") \
            for (int mf_ = 0; mf_ < 4; ++mf_) { \
                afr[mf_][0] = *reinterpret_cast<const bf16x8*>(Ab_ + arow[mf_] + kx0); \
                afr[mf_][1] = *reinterpret_cast<const bf16x8*>(Ab_ + arow[mf_] + kx1); \
            } \
        } \
        bf16x8 bfv[2][2]; \
        _Pragma("unroll") \
        for (int nf_ = 0; nf_ < 2; ++nf_) { \
            bfv[nf_][0] = *reinterpret_cast<const bf16x8*>(Bb_ + brow[nf_] + kx0); \
            bfv[nf_][1] = *reinterpret_cast<const bf16x8*>(Bb_ + brow[nf_] + kx1); \
        } \
        STG_STMT; \
        WAIT_STMT; \
        SBAR; \
        LG0; \
        __builtin_amdgcn_sched_barrier(0); \
        __builtin_amdgcn_s_setprio(1); \
        _Pragma("unroll") \
        for (int mf_ = 0; mf_ < 4; ++mf_) { \
            _Pragma("unroll") \
            for (int nf_ = 0; nf_ < 2; ++nf_) { \
                acc[MH][NH][mf_][nf_] = __builtin_amdgcn_mfma_f32_16x16x32_bf16(afr[mf_][0], bfv[nf_][0], acc[MH][NH][mf_][nf_], 0, 0, 0); \
                acc[MH][NH][mf_][nf_] = __builtin_amdgcn_mfma_f32_16x16x32_bf16(afr[mf_][1], bfv[nf_][1], acc[MH][NH][mf_][nf_], 0, 0, 0); \
            } \
        } \
        __builtin_amdgcn_s_setprio(0); \
        SBAR; \
    } while (0)

    STAGE(0, 0, 0, 0);
    STAGE(0, 1, 0, 0);
    STAGE(0, 0, 1, 0);
    STAGE(0, 1, 1, 0);
    STAGE(1, 0, 0, 1);
    STAGE(1, 1, 0, 1);
    VM_WAIT(4);
    SBAR;
    __builtin_amdgcn_sched_barrier(0);

#pragma unroll 1
    for (int i = 0; i < 7; ++i) {
        const int T1 = 2*i + 1, T2 = 2*i + 2, T3 = 2*i + 3;
        PH(0, 0, 0, STAGE(1, 0, 1, T1), ;);            // ph1
        PH(0, 0, 1, STAGE(1, 1, 1, T1), ;);            // ph2
        PH(0, 1, 0, STAGE(0, 0, 0, T2), ;);            // ph3
        PH(0, 1, 1, STAGE(0, 1, 0, T2), VM_WAIT(4));   // ph4
        PH(1, 0, 0, STAGE(0, 0, 1, T2), ;);            // ph5
        PH(1, 0, 1, STAGE(0, 1, 1, T2), ;);            // ph6
        PH(1, 1, 0, STAGE(1, 0, 0, T3), ;);            // ph7
        PH(1, 1, 1, STAGE(1, 1, 0, T3), VM_WAIT(4));   // ph8
    }
    PH(0, 0, 0, STAGE(1, 0, 1, 15), ;);
    PH(0, 0, 1, STAGE(1, 1, 1, 15), ;);
    PH(0, 1, 0, ;, ;);
    PH(0, 1, 1, ;, VM_WAIT(0));
    PH(1, 0, 0, ;, ;);
    PH(1, 0, 1, ;, ;);
    PH(1, 1, 0, ;, ;);
    PH(1, 1, 1, ;, ;);
#undef PH
#undef STAGE

    // ---- epilogue ----
    const int bblk = m0 >> 12;          // batch index (BM=256 divides 4096)
    const int sloc = m0 & 4095;         // s-offset within batch
#pragma unroll
    for (int mh = 0; mh < 2; ++mh) {
#pragma unroll
    for (int nh = 0; nh < 2; ++nh) {
#pragma unroll
    for (int mf = 0; mf < 4; ++mf) {
#pragma unroll
        for (int nf = 0; nf < 2; ++nf) {
            const int gn = n0 + nh*128 + wqc*32 + nf*16 + fr;
            const int mb = mh*128 + wqr*64 + mf*16 + cg*4;
            if (EPI == 2 || EPI == 3) {
                // transposed bf16 out: row = e-index gn, cols = s (contig)
                ushort4 o;
#pragma unroll
                for (int r = 0; r < 4; ++r) {
                    float x = acc[mh][nh][mf][nf][r] + bias_v[nh][nf];
                    if (EPI == 2) {
                        x = fmaxf(x, 0.f) + kEPS;
                        if (mask[m0 + mb + r]) x = 0.f;
                    }
                    ((u16*)&o)[r] = f2bf(x);
                }
                *reinterpret_cast<ushort4*>(Cb + ((size_t)(bblk*1024 + gn))*4096 + sloc + mb) = o;
            } else {
#pragma unroll
                for (int r = 0; r < 4; ++r) {
                    const int gm = m0 + mb + r;
                    float x = acc[mh][nh][mf][nf][r] + bias_v[nh][nf];
                    if (EPI == 0) {
                        Cf[(size_t)gm*E_ + gn] = x;
                    } else {
                        x = fmaxf(x, 0.f) + kEPS;
                        Cb[(size_t)gm*E_ + gn] = f2bf(x);
                    }
                }
            }
        }
    }
    }
    }
}

// ---- kv_context via MFMA: kvT[v][d] = sum_s VvT[v][s] * KaT[d][s] ----
// grid (64 bh, 8 sc); 256 thr = 4 waves; wave w -> C rows v = w*16..+15.
// Fragments read directly from global (4-lane groups = 64B segments).
#define NSC 8
#define KCH (S_/NSC)       // 512 s per block
__global__ __launch_bounds__(256)
void kv_mfma_kernel(const u16* __restrict__ KaT, const u16* __restrict__ VvT,
                    float* __restrict__ kvp, float* __restrict__ ksp)
{
    __shared__ float sm[4][64];
    const int bh = blockIdx.x, sc = blockIdx.y;
    const int tid = threadIdx.x;
    const int w = tid >> 6, lane = tid & 63;
    const int fr = lane & 15, cg = lane >> 4;

    const u16* Ar = VvT + ((size_t)bh*64 + w*16 + fr)*4096 + sc*KCH;
    const u16* Br0 = KaT + ((size_t)bh*64 + fr)*4096 + sc*KCH;

    f32x4 acc[4] = {};
#pragma unroll 2
    for (int ks = 0; ks < KCH/32; ++ks) {
        const int ko = ks*32 + cg*8;
        bf16x8 af = *reinterpret_cast<const bf16x8*>(Ar + ko);
#pragma unroll
        for (int nf = 0; nf < 4; ++nf) {
            bf16x8 bf = *reinterpret_cast<const bf16x8*>(Br0 + (size_t)nf*16*4096 + ko);
            acc[nf] = __builtin_amdgcn_mfma_f32_16x16x32_bf16(af, bf, acc[nf], 0, 0, 0);
        }
    }
    float* dst = kvp + ((size_t)sc*64 + bh)*4096;
#pragma unroll
    for (int nf = 0; nf < 4; ++nf)
#pragma unroll
        for (int r = 0; r < 4; ++r)
            dst[(w*16 + cg*4 + r)*64 + nf*16 + fr] = acc[nf][r];

    // ksum partial: row sums of KaT over this s-chunk (L2-hot)
    {
        const int d = tid & 63, qq = tid >> 6;
        const u16* kr = KaT + ((size_t)bh*64 + d)*4096 + sc*KCH + qq*(KCH/4);
        float s = 0.f;
#pragma unroll 4
        for (int i = 0; i < KCH/4/8; ++i) {
            bf16x8 kk = *reinterpret_cast<const bf16x8*>(kr + i*8);
#pragma unroll
            for (int j = 0; j < 8; ++j) s += (float)kk[j];
        }
        sm[qq][d] = s;
    }
    __syncthreads();
    if (tid < 64)
        ksp[((size_t)sc*64 + bh)*64 + tid] = sm[0][tid] + sm[1][tid] + sm[2][tid] + sm[3][tid];
}

// ---- reduce partials: kvT bf16 [bh][v][d] + ksum ----
__global__ __launch_bounds__(256)
void kv_reduce_kernel(const float* __restrict__ kvp, const float* __restrict__ ksp,
                      u16* __restrict__ kvT, float* __restrict__ ksum)
{
    const int i = blockIdx.x*256 + threadIdx.x;   // 262144
    float s = 0.f;
#pragma unroll
    for (int c = 0; c < NSC; ++c) s += kvp[(size_t)c*262144 + i];
    kvT[i] = f2bf(s);
    if (i < 4096) {
        float t = 0.f;
#pragma unroll
        for (int c = 0; c < NSC; ++c) t += ksp[(size_t)c*4096 + i];
        ksum[i] = t;
    }
}

// ---------------- stage 3: attn = (Qa @ kv) / max(Qa . ksum, eps), MFMA ----------------
__global__ __launch_bounds__(256)
void attn_kernel(const u16* __restrict__ Qa, const u16* __restrict__ kvT,
                 const float* __restrict__ ksum, u16* __restrict__ attn)
{
    __shared__ u16  Qs[256*64];
    __shared__ u16  Ts[64*64];
    __shared__ float kss[64];
    __shared__ float invd[256];

    const int bh = blockIdx.x, b = bh >> 4, h = bh & 15;
    const int s0 = blockIdx.y * 256;
    const int tid = threadIdx.x;
    const int wid = tid >> 6, lane = tid & 63;
    const int fr = lane & 15, cg = lane >> 4;

#pragma unroll
    for (int j = 0; j < 8; ++j) {
        int L = (wid*8 + j)*64 + lane;
        int row = L >> 3, c = L & 7;
        int cs = c ^ (row & 7);
        const u16* src = Qa + (size_t)(b*S_ + s0 + row)*E_ + h*64 + cs*8;
        __builtin_amdgcn_global_load_lds((gaddr_t)src, (laddr_t)(Qs + L*8), 16, 0, 0);
    }
#pragma unroll
    for (int k = 0; k < 2; ++k) {
        int g = k*256 + tid;
        int v = g >> 3, c = g & 7;
        uint4 q = *reinterpret_cast<const uint4*>(kvT + (size_t)bh*4096 + g*8);
        int cs = c ^ (v & 7);
        *reinterpret_cast<uint4*>(Ts + v*64 + cs*8) = q;
    }
    if (tid < 64) kss[tid] = ksum[bh*64 + tid];
    asm volatile("s_waitcnt vmcnt(0) lgkmcnt(0)" ::: "memory");
    __syncthreads();

    {
        float den = 0.f;
#pragma unroll
        for (int c = 0; c < 8; ++c) {
            uint4 qc = *reinterpret_cast<const uint4*>(Qs + tid*64 + (c ^ (tid & 7))*8);
            den += lo2f(qc.x)*kss[c*8+0] + hi2f(qc.x)*kss[c*8+1]
                 + lo2f(qc.y)*kss[c*8+2] + hi2f(qc.y)*kss[c*8+3]
                 + lo2f(qc.z)*kss[c*8+4] + hi2f(qc.z)*kss[c*8+5]
                 + lo2f(qc.w)*kss[c*8+6] + hi2f(qc.w)*kss[c*8+7];
        }
        invd[tid] = 1.0f / fmaxf(den, kEPS);
    }
    __syncthreads();

    f32x4 acc[4][4] = {};
#pragma unroll
    for (int ks = 0; ks < 2; ++ks) {
        bf16x8 bfrag[4];
#pragma unroll
        for (int nf = 0; nf < 4; ++nf) {
            int v = nf*16 + fr;
            bfrag[nf] = *reinterpret_cast<const bf16x8*>(Ts + v*64 + ((ks*4 + cg) ^ (v & 7))*8);
        }
#pragma unroll
        for (int mf = 0; mf < 4; ++mf) {
            int m = wid*64 + mf*16 + fr;
            bf16x8 afrag = *reinterpret_cast<const bf16x8*>(Qs + m*64 + ((ks*4 + cg) ^ (m & 7))*8);
#pragma unroll
            for (int nf = 0; nf < 4; ++nf)
                acc[mf][nf] = __builtin_amdgcn_mfma_f32_16x16x32_bf16(afrag, bfrag[nf], acc[mf][nf], 0, 0, 0);
        }
    }

#pragma unroll
    for (int mf = 0; mf < 4; ++mf) {
#pragma unroll
        for (int nf = 0; nf < 4; ++nf) {
            const int v = nf*16 + fr;
#pragma unroll
            for (int r = 0; r < 4; ++r) {
                const int row = wid*64 + mf*16 + cg*4 + r;
                float x = acc[mf][nf][r] * invd[row];
                attn[(size_t)(b*S_ + s0 + row)*E_ + h*64 + v] = f2bf(x);
            }
        }
    }
}

// ---------------- host ----------------
extern "C" void kernel_launch(void* const* d_in, const int* in_sizes, int n_in,
                              void* d_out, int out_size, void* d_ws, size_t ws_size,
                              hipStream_t stream)
{
    const float* query = (const float*)d_in[0];
    const float* key   = (const float*)d_in[1];
    const float* value = (const float*)d_in[2];
    const u8*    mask  = (const u8*)d_in[3];
    const float* Wq = (const float*)d_in[4];
    const float* bq = (const float*)d_in[5];
    const float* Wk = (const float*)d_in[6];
    const float* bk = (const float*)d_in[7];
    const float* Wv = (const float*)d_in[8];
    const float* bv = (const float*)d_in[9];
    const float* Wo = (const float*)d_in[10];
    const float* bo = (const float*)d_in[11];
    float* out = (float*)d_out;

    const size_t SZ_ME = (size_t)M_ * E_;
    const size_t SZ_EE = (size_t)E_ * E_;

    char* ws = (char*)d_ws;
    u16* qx   = (u16*)ws; ws += SZ_ME*2;   // query bf16; reused for attnb
    u16* kx   = (u16*)ws; ws += SZ_ME*2;   // key bf16; reused for kvp
    u16* vx   = (u16*)ws; ws += SZ_ME*2;   // value bf16; reused for ksp/kvT/ksum
    u16* Qa   = (u16*)ws; ws += SZ_ME*2;
    u16* KaT  = (u16*)ws; ws += SZ_ME*2;   // [b*1024+h*64+d][4096] bf16
    u16* VvT  = (u16*)ws; ws += SZ_ME*2;   // [b*1024+h*64+v][4096] bf16
    u16* wqb  = (u16*)ws; ws += SZ_EE*2;
    u16* wkb  = (u16*)ws; ws += SZ_EE*2;
    u16* wvb  = (u16*)ws; ws += SZ_EE*2;
    u16* wob  = (u16*)ws; ws += SZ_EE*2;

    // overlays (dead by the time they're written)
    u16*   attnb = qx;
    float* kvp   = (float*)kx;                                  // 8 MiB
    float* ksp   = (float*)vx;                                  // 128 KiB
    u16*   kvT   = (u16*)((char*)vx + (size_t)NSC*4096*4);      // 512 KiB
    float* ksum  = (float*)((char*)kvT + (size_t)64*4096*2);    // 16 KiB

    // 1) conversions to bf16
    cvt_kernel<<<(int)(SZ_ME/4/256), 256, 0, stream>>>(query, qx, (int)(SZ_ME/4));
    cvt_kernel<<<(int)(SZ_ME/4/256), 256, 0, stream>>>(key,   kx, (int)(SZ_ME/4));
    cvt_kernel<<<(int)(SZ_ME/4/256), 256, 0, stream>>>(value, vx, (int)(SZ_ME/4));
    cvt_kernel<<<(int)(SZ_EE/4/256), 256, 0, stream>>>(Wq, wqb, (int)(SZ_EE/4));
    cvt_kernel<<<(int)(SZ_EE/4/256), 256, 0, stream>>>(Wk, wkb, (int)(SZ_EE/4));
    cvt_kernel<<<(int)(SZ_EE/4/256), 256, 0, stream>>>(Wv, wvb, (int)(SZ_EE/4));
    cvt_kernel<<<(int)(SZ_EE/4/256), 256, 0, stream>>>(Wo, wob, (int)(SZ_EE/4));

    // 2) QKV projections (8-phase GEMM); K,V write transposed per-head layouts
    dim3 ggrid(M_/BM, E_/BN);
    constexpr size_t LDS_BYTES = 2 * 32768 * sizeof(u16);   // 128 KB
    gemm8<1><<<ggrid, 512, LDS_BYTES, stream>>>(qx, wqb, bq, nullptr, nullptr, Qa);
    gemm8<2><<<ggrid, 512, LDS_BYTES, stream>>>(kx, wkb, bk, mask,    nullptr, KaT);
    gemm8<3><<<ggrid, 512, LDS_BYTES, stream>>>(vx, wvb, bv, nullptr, nullptr, VvT);

    // 3) kv_context + k_sum via MFMA (two-phase, deterministic)
    kv_mfma_kernel<<<dim3(64, NSC), 256, 0, stream>>>(KaT, VvT, kvp, ksp);
    kv_reduce_kernel<<<1024, 256, 0, stream>>>(kvp, ksp, kvT, ksum);

    // 4) attn numerator / denom (MFMA)
    attn_kernel<<<dim3(B_*H_, S_/256), 256, 0, stream>>>(Qa, kvT, ksum, attnb);

    // 5) output projection -> f32 out
    gemm8<0><<<ggrid, 512, LDS_BYTES, stream>>>(attnb, wob, bo, nullptr, out, nullptr);
}